// Round 8
// baseline (407.974 us; speedup 1.0000x reference)
//
#include <hip/hip_runtime.h>
#include <stdint.h>

// Problem constants (reference: B=8, Q=2048, K=2048, D=512)
#define BB 8
#define QQ 2048
#define KK 2048
#define DD 512

typedef _Float16 f16x8 __attribute__((ext_vector_type(8)));
typedef float f32x4 __attribute__((ext_vector_type(4)));

__device__ __forceinline__ unsigned short f2h(float f) {
    union { _Float16 h; unsigned short u; } x;
    x.h = (_Float16)f;
    return x.u;
}
__device__ __forceinline__ float h2f(unsigned short u) {
    union { unsigned short u; _Float16 h; } x;
    x.u = u;
    return (float)x.h;
}

// async global->LDS, 16 B per lane; lds is wave-uniform base, HW scatters
// lane l to lds + l*16 (m97/m104 semantics).
__device__ __forceinline__ void async16(const unsigned short* g, unsigned short* l) {
    __builtin_amdgcn_global_load_lds(
        (const __attribute__((address_space(1))) unsigned int*)g,
        (__attribute__((address_space(3))) unsigned int*)l, 16, 0, 0);
}

// ---------------------------------------------------------------------------
// fp32 -> fp16 convert, 8 elems/thread, TWO tensors in one launch (y-dim).
// ---------------------------------------------------------------------------
__global__ __launch_bounds__(256) void cvt_f32_f16_2(const float* __restrict__ in0,
                                                     const float* __restrict__ in1,
                                                     unsigned short* __restrict__ out0,
                                                     unsigned short* __restrict__ out1) {
    const float* in = blockIdx.y ? in1 : in0;
    unsigned short* out = blockIdx.y ? out1 : out0;
    size_t i = ((size_t)blockIdx.x * 256 + threadIdx.x) * 8;
    float4 a = *(const float4*)(in + i);
    float4 b = *(const float4*)(in + i + 4);
    uint4 u;
    u.x = (unsigned)f2h(a.x) | ((unsigned)f2h(a.y) << 16);
    u.y = (unsigned)f2h(a.z) | ((unsigned)f2h(a.w) << 16);
    u.z = (unsigned)f2h(b.x) | ((unsigned)f2h(b.y) << 16);
    u.w = (unsigned)f2h(b.z) | ((unsigned)f2h(b.w) << 16);
    *(uint4*)(out + i) = u;
}

// ---------------------------------------------------------------------------
// Tiled transpose + convert: in[R][C] fp32 -> out[C][R] fp16 (32x32 tiles)
// ---------------------------------------------------------------------------
__global__ __launch_bounds__(256) void transpose_cvt(const float* __restrict__ in,
                                                     unsigned short* __restrict__ out,
                                                     int R, int C, long inB, long outB) {
    __shared__ float t[32][33];
    const float* ip = in + (size_t)blockIdx.z * inB;
    unsigned short* op = out + (size_t)blockIdx.z * outB;
    int x = threadIdx.x & 31, y0 = threadIdx.x >> 5;   // 32 x 8
    int c0 = blockIdx.x * 32, r0 = blockIdx.y * 32;
#pragma unroll
    for (int i = 0; i < 32; i += 8)
        t[y0 + i][x] = ip[(size_t)(r0 + y0 + i) * C + c0 + x];
    __syncthreads();
#pragma unroll
    for (int i = 0; i < 32; i += 8)
        op[(size_t)(c0 + y0 + i) * R + r0 + x] = f2h(t[x][y0 + i]);
}

// ---------------------------------------------------------------------------
// 128x128 NT GEMM, 4 waves (2M x 2N, wave tile 64x64 = m97-verified frag
// geometry: 8 ds_read_b128 per 16 MFMA, ratio 2.0), BK=32, ring-3 LDS
// (48 KiB -> 3 blocks/CU = 12 waves/CU), prefetch distance 2, counted
// vmcnt(4) gate (4 loads/wave/tile, never 0 in steady state), ONE s_barrier
// per K-tile, setprio'd 16-MFMA cluster, both-sides slot swizzle
// LDS[r][s] = G[r][s ^ ((r>>1)&3)].
// OUTM 0: f16 out (qW).  OUTM 2: fp32 out scaled by 1/sums[row] (context).
// ---------------------------------------------------------------------------
template <int OUTM>
__global__ __launch_bounds__(256) void gemm128t(
    const unsigned short* __restrict__ Aall, const unsigned short* __restrict__ Ball,
    void* __restrict__ Call, const float* __restrict__ sums,
    int Kred, int lda, int ldb, int ldc,
    long aStride, long bStride, long cStride) {
    // ---- bijective XCD swizzle (m204) ----
    const int gx = gridDim.x, gy = gridDim.y;
    const int nwg = gx * gy * (int)gridDim.z;
    const int p = ((int)blockIdx.z * gy + (int)blockIdx.y) * gx + (int)blockIdx.x;
    const int qch = nwg >> 3, rch = nwg & 7;
    const int xcd = p & 7, ooff = p >> 3;
    const int w = (xcd < rch ? xcd * (qch + 1) : rch * (qch + 1) + (xcd - rch) * qch) + ooff;
    const int b = w / (gx * gy);
    const int rem = w - b * (gx * gy);
    const int my = rem / gx;
    const int nx = rem - my * gx;
    const int m0 = my * 128;
    const int n0 = nx * 128;

    __shared__ unsigned short As[3][128 * 32];   // 24 KiB
    __shared__ unsigned short Bs[3][128 * 32];   // 24 KiB

    const int tid = threadIdx.x;
    const int lane = tid & 63, wv = tid >> 6;    // 4 waves
    const int wm = wv >> 1, wn = wv & 1;         // 2M x 2N wave grid
    const int lrow = lane & 15, quad = lane >> 4;

    const int sr = lane >> 2;                    // row within 16-row chunk
    const int ssl = (lane & 3) ^ ((sr >> 1) & 3);  // pre-swizzled source slot
    const unsigned short* Ab = Aall + (size_t)b * aStride + (size_t)m0 * lda;
    const unsigned short* Bb = Ball + (size_t)b * bStride + (size_t)n0 * ldb;

    const int NT = Kred >> 5;

    // per wave per tile: 2 A-chunks + 2 B-chunks (chunk = 16 rows x 32 cols),
    // wave wv covers rows [wv*16 + j*64, ...) -- 4 waves x 2 calls = 128 rows.
    auto stage = [&](int t, int slot) {
#pragma unroll
        for (int j = 0; j < 2; j++) {
            const int c = wv + j * 4;            // chunk 0..7
            const int r = c * 16 + sr;
            async16(Ab + (size_t)r * lda + t * 32 + ssl * 8, &As[slot][c * 512]);
        }
#pragma unroll
        for (int j = 0; j < 2; j++) {
            const int c = wv + j * 4;
            const int r = c * 16 + sr;
            async16(Bb + (size_t)r * ldb + t * 32 + ssl * 8, &Bs[slot][c * 512]);
        }
    };

    f32x4 acc[4][4];
#pragma unroll
    for (int mi = 0; mi < 4; mi++)
#pragma unroll
        for (int ni = 0; ni < 4; ni++)
            acc[mi][ni] = (f32x4){0.f, 0.f, 0.f, 0.f};

    // prologue: stage tiles 0,1 (8 loads/wave in flight)
    stage(0, 0);
    if (NT > 1) stage(1, 1);

    const int rsw = (lrow >> 1) & 3;
    int sl = 0, slp = 2;                         // current slot, prefetch slot

    for (int t = 0; t < NT; ++t) {
        // gate: tile t's 4 loads retired; tile t+1's 4 may stay in flight
        if (t + 1 < NT) asm volatile("s_waitcnt vmcnt(4)" ::: "memory");
        else            asm volatile("s_waitcnt vmcnt(0)" ::: "memory");
        __builtin_amdgcn_s_barrier();
        __builtin_amdgcn_sched_barrier(0);

        const unsigned short* Asl = As[sl];
        const unsigned short* Bsl = Bs[sl];

        if (t + 2 < NT) stage(t + 2, slp);       // prefetch into ring

        f16x8 af[4], bfr[4];
#pragma unroll
        for (int i = 0; i < 4; i++)
            af[i] = *(const f16x8*)&Asl[(wm * 64 + i * 16 + lrow) * 32 + ((quad ^ rsw) * 8)];
#pragma unroll
        for (int i = 0; i < 4; i++)
            bfr[i] = *(const f16x8*)&Bsl[(wn * 64 + i * 16 + lrow) * 32 + ((quad ^ rsw) * 8)];

        __builtin_amdgcn_s_setprio(1);
#pragma unroll
        for (int mi = 0; mi < 4; mi++)
#pragma unroll
            for (int ni = 0; ni < 4; ni++)
                acc[mi][ni] = __builtin_amdgcn_mfma_f32_16x16x32_f16(af[mi], bfr[ni],
                                                                     acc[mi][ni], 0, 0, 0);
        __builtin_amdgcn_s_setprio(0);

        sl = (sl == 2) ? 0 : sl + 1;
        slp = (slp == 2) ? 0 : slp + 1;
    }

    // ---- epilogue ----
#pragma unroll
    for (int mi = 0; mi < 4; mi++) {
        const int gm = m0 + wm * 64 + mi * 16 + quad * 4;
        if constexpr (OUTM == 0) {
            unsigned short* C = (unsigned short*)Call + (size_t)b * cStride;
#pragma unroll
            for (int ni = 0; ni < 4; ni++) {
                int gn = n0 + wn * 64 + ni * 16 + lrow;
#pragma unroll
                for (int r = 0; r < 4; r++)
                    C[(size_t)(gm + r) * ldc + gn] = f2h(acc[mi][ni][r]);
            }
        } else {
            float* C = (float*)Call + (size_t)b * cStride;
            const float* s = sums + (size_t)b * QQ;
            float iv[4];
#pragma unroll
            for (int r = 0; r < 4; r++) iv[r] = 1.0f / s[gm + r];
#pragma unroll
            for (int ni = 0; ni < 4; ni++) {
                int gn = n0 + wn * 64 + ni * 16 + lrow;
#pragma unroll
                for (int r = 0; r < 4; r++)
                    C[(size_t)(gm + r) * ldc + gn] = acc[mi][ni][r] * iv[r];
            }
        }
    }
}

// ---------------------------------------------------------------------------
// Deep-pipelined 256x256 NT GEMM with exp/mask/rowsum epilogue (scores step).
// HW-verified in R5. 8 waves (2M x 4N), BK=32, quad-buffered LDS ring,
// prefetch distance 3, counted vmcnt gates (8/4/0), ONE raw s_barrier per
// K-tile, setprio'd 16-MFMA clusters, both-sides slot swizzle.
// ---------------------------------------------------------------------------
__global__ __launch_bounds__(512, 2) void gemm256_exp(
    const unsigned short* __restrict__ Aall, const unsigned short* __restrict__ Ball,
    unsigned short* __restrict__ Call, const int* __restrict__ maskAll,
    float* __restrict__ sums, int Kred, int lda, int ldb, int ldc,
    long aStride, long bStride, long cStride, int maskStride, float scale) {
    // ---- bijective XCD swizzle ----
    const int gx = gridDim.x, gy = gridDim.y;
    const int nwg = gx * gy * (int)gridDim.z;
    const int p = ((int)blockIdx.z * gy + (int)blockIdx.y) * gx + (int)blockIdx.x;
    const int qch = nwg >> 3, rch = nwg & 7;
    const int xcd = p & 7, ooff = p >> 3;
    const int w = (xcd < rch ? xcd * (qch + 1) : rch * (qch + 1) + (xcd - rch) * qch) + ooff;
    const int b = w / (gx * gy);
    const int rem = w - b * (gx * gy);
    const int my = rem / gx;
    const int nx = rem - my * gx;
    const int m0 = my * 256;
    const int n0 = nx * 256;

    __shared__ unsigned short As[4][256 * 32];   // 64 KiB ring
    __shared__ unsigned short Bs[4][256 * 32];   // 64 KiB ring

    const int tid = threadIdx.x;
    const int lane = tid & 63, wv = tid >> 6;    // 8 waves
    const int wm = wv >> 2, wn = wv & 3;         // 2 x 4 wave grid
    const int lrow = lane & 15, quad = lane >> 4;

    const int sr = lane >> 2;
    const int ssl = (lane & 3) ^ ((sr >> 1) & 3);
    const unsigned short* Ab = Aall + (size_t)b * aStride + (size_t)m0 * lda;
    const unsigned short* Bb = Ball + (size_t)b * bStride + (size_t)n0 * ldb;

    const int NT = Kred >> 5;

    auto stageA = [&](int t) {
#pragma unroll
        for (int j = 0; j < 2; j++) {
            const int c = wv * 2 + j;
            const int r = c * 16 + sr;
            async16(Ab + (size_t)r * lda + t * 32 + ssl * 8, &As[t & 3][c * 512]);
        }
    };
    auto stageB = [&](int t) {
#pragma unroll
        for (int j = 0; j < 2; j++) {
            const int c = wv * 2 + j;
            const int r = c * 16 + sr;
            async16(Bb + (size_t)r * ldb + t * 32 + ssl * 8, &Bs[t & 3][c * 512]);
        }
    };

    f32x4 acc[8][4];
#pragma unroll
    for (int mi = 0; mi < 8; mi++)
#pragma unroll
        for (int ni = 0; ni < 4; ni++)
            acc[mi][ni] = (f32x4){0.f, 0.f, 0.f, 0.f};

    for (int tt = 0; tt < 3 && tt < NT; ++tt) { stageA(tt); stageB(tt); }

    const int rsw = (lrow >> 1) & 3;

    for (int t = 0; t < NT; ++t) {
        if (t + 2 < NT)      asm volatile("s_waitcnt vmcnt(8)" ::: "memory");
        else if (t + 1 < NT) asm volatile("s_waitcnt vmcnt(4)" ::: "memory");
        else                 asm volatile("s_waitcnt vmcnt(0)" ::: "memory");
        __builtin_amdgcn_s_barrier();
        __builtin_amdgcn_sched_barrier(0);

        const unsigned short* Asl = As[t & 3];
        const unsigned short* Bsl = Bs[t & 3];
        f16x8 af[4], bfr[4];

        if (t + 3 < NT) stageA(t + 3);
#pragma unroll
        for (int ni = 0; ni < 4; ni++)
            bfr[ni] = *(const f16x8*)&Bsl[(wn * 64 + ni * 16 + lrow) * 32 + ((quad ^ rsw) * 8)];
#pragma unroll
        for (int mi = 0; mi < 4; mi++)
            af[mi] = *(const f16x8*)&Asl[(wm * 128 + mi * 16 + lrow) * 32 + ((quad ^ rsw) * 8)];
        __builtin_amdgcn_s_setprio(1);
#pragma unroll
        for (int mi = 0; mi < 4; mi++)
#pragma unroll
            for (int ni = 0; ni < 4; ni++)
                acc[mi][ni] = __builtin_amdgcn_mfma_f32_16x16x32_f16(af[mi], bfr[ni],
                                                                     acc[mi][ni], 0, 0, 0);
        __builtin_amdgcn_s_setprio(0);

        if (t + 3 < NT) stageB(t + 3);
#pragma unroll
        for (int mi = 0; mi < 4; mi++)
            af[mi] = *(const f16x8*)&Asl[(wm * 128 + (mi + 4) * 16 + lrow) * 32 + ((quad ^ rsw) * 8)];
        __builtin_amdgcn_s_setprio(1);
#pragma unroll
        for (int mi = 0; mi < 4; mi++)
#pragma unroll
            for (int ni = 0; ni < 4; ni++)
                acc[mi + 4][ni] = __builtin_amdgcn_mfma_f32_16x16x32_f16(af[mi], bfr[ni],
                                                                         acc[mi + 4][ni], 0, 0, 0);
        __builtin_amdgcn_s_setprio(0);
    }

    // ---- epilogue: e = mask ? exp(acc*scale) : 0 -> f16 out; rowsum atomics ----
    unsigned short* C = Call + (size_t)b * cStride;
    const int* mk = maskAll + (size_t)b * maskStride;
#pragma unroll
    for (int mi = 0; mi < 8; mi++) {
        const int gm = m0 + wm * 128 + mi * 16 + quad * 4;
        float ps[4] = {0.f, 0.f, 0.f, 0.f};
#pragma unroll
        for (int ni = 0; ni < 4; ni++) {
            int gn = n0 + wn * 64 + ni * 16 + lrow;
            bool keep = mk[gn] != 0;
#pragma unroll
            for (int r = 0; r < 4; r++) {
                float e = keep ? __expf(acc[mi][ni][r] * scale) : 0.f;
                C[(size_t)(gm + r) * ldc + gn] = f2h(e);
                ps[r] += e;
            }
        }
#pragma unroll
        for (int off = 1; off < 16; off <<= 1)
#pragma unroll
            for (int r = 0; r < 4; r++) ps[r] += __shfl_xor(ps[r], off);
        if (lrow == 0) {
            float* s = sums + (size_t)b * QQ;
#pragma unroll
            for (int r = 0; r < 4; r++) atomicAdd(&s[gm + r], ps[r]);
        }
    }
}

// ---------------------------------------------------------------------------
// dist[row,:] = expS[row,:] * (1/sums[row]).  One block per row of 2048.
// ---------------------------------------------------------------------------
__global__ __launch_bounds__(256) void normalize_rows(const unsigned short* __restrict__ expS,
                                                      const float* __restrict__ sums,
                                                      float* __restrict__ dist) {
    const unsigned short* sp = expS + (size_t)blockIdx.x * 2048;
    float* dp = dist + (size_t)blockIdx.x * 2048;
    const float inv = 1.0f / sums[blockIdx.x];
    int tid = threadIdx.x;

    uint4 u = *(const uint4*)(sp + tid * 8);
    float4 o0, o1;
    o0.x = h2f((unsigned short)(u.x & 0xffff)) * inv;
    o0.y = h2f((unsigned short)(u.x >> 16)) * inv;
    o0.z = h2f((unsigned short)(u.y & 0xffff)) * inv;
    o0.w = h2f((unsigned short)(u.y >> 16)) * inv;
    o1.x = h2f((unsigned short)(u.z & 0xffff)) * inv;
    o1.y = h2f((unsigned short)(u.z >> 16)) * inv;
    o1.z = h2f((unsigned short)(u.w & 0xffff)) * inv;
    o1.w = h2f((unsigned short)(u.w >> 16)) * inv;
    *(float4*)(dp + tid * 8) = o0;
    *(float4*)(dp + tid * 8 + 4) = o1;
}

// ---------------------------------------------------------------------------
extern "C" void kernel_launch(void* const* d_in, const int* in_sizes, int n_in,
                              void* d_out, int out_size, void* d_ws, size_t ws_size,
                              hipStream_t stream) {
    const float* q    = (const float*)d_in[0];   // [B,Q,D]
    const float* k    = (const float*)d_in[1];   // [B,K,D]
    const float* v    = (const float*)d_in[2];   // [B,K,D]
    const int*   mask = (const int*)d_in[3];     // [B,K]
    const float* W    = (const float*)d_in[4];   // [D,D]

    float* ctx  = (float*)d_out;                           // [B,Q,D]
    float* dist = ctx + (size_t)BB * QQ * DD;              // [B,Q,K]

    // workspace layout (f16 = unsigned short), ~135 MiB
    unsigned short* ws  = (unsigned short*)d_ws;
    unsigned short* Wt  = ws;                                   // [D][D]   (W^T)
    unsigned short* Qh  = Wt + (size_t)DD * DD;                 // [B][Q][D]
    unsigned short* Kh  = Qh + (size_t)BB * QQ * DD;            // [B][K][D]
    unsigned short* Vt  = Kh + (size_t)BB * KK * DD;            // [B][D][K] (V^T)
    unsigned short* qWh = Vt + (size_t)BB * DD * KK;            // [B][Q][D]
    unsigned short* Sc  = qWh + (size_t)BB * QQ * DD;           // [B][Q][K] expS f16
    float* sums = (float*)(Sc + (size_t)BB * QQ * KK);          // [B][Q]

    const float scale = 0.044194173824159216f;  // 1/sqrt(512)

    // 0) zero the row-sum accumulators (graph-capture-legal async memset)
    (void)hipMemsetAsync(sums, 0, (size_t)BB * QQ * sizeof(float), stream);
    // 1) W -> W^T f16
    transpose_cvt<<<dim3(DD / 32, DD / 32, 1), 256, 0, stream>>>(W, Wt, DD, DD, 0, 0);
    // 2) query, key -> f16 (single launch)
    cvt_f32_f16_2<<<dim3((BB * QQ * DD / 8) / 256, 2), 256, 0, stream>>>(q, k, Qh, Kh);
    // 3) value -> V^T f16
    transpose_cvt<<<dim3(DD / 32, KK / 32, BB), 256, 0, stream>>>(
        v, Vt, KK, DD, (long)KK * DD, (long)DD * KK);
    // 4) qW[b] = Q[b] @ W: M=Q, N=D, Kred=D -> f16 (4-wave 128-tile pipelined)
    gemm128t<0><<<dim3(DD / 128, QQ / 128, BB), 256, 0, stream>>>(
        Qh, Wt, qWh, nullptr, DD, DD, DD, DD,
        (long)QQ * DD, 0, (long)QQ * DD);
    // 5) expS[b] = exp(scale * qW[b] @ key[b]^T) (masked->0) + row sums
    gemm256_exp<<<dim3(KK / 256, QQ / 256, BB), 512, 0, stream>>>(
        qWh, Kh, Sc, mask, sums, DD, DD, DD, KK,
        (long)QQ * DD, (long)KK * DD, (long)QQ * KK, KK, scale);
    // 6) dist = expS / rowsum  (fp32 output)
    normalize_rows<<<dim3(BB * QQ), 256, 0, stream>>>(Sc, sums, dist);
    // 7) context[b] = (expS[b] @ value[b]) / rowsum (4-wave 128-tile pipelined)
    gemm128t<2><<<dim3(DD / 128, QQ / 128, BB), 256, 0, stream>>>(
        Sc, Vt, ctx, sums, KK, KK, KK, DD,
        (long)QQ * KK, (long)DD * KK, (long)QQ * DD);
}

// Round 9
// 388.474 us; speedup vs baseline: 1.0502x; 1.0502x over previous
//
#include <hip/hip_runtime.h>
#include <stdint.h>

// Problem constants (reference: B=8, Q=2048, K=2048, D=512)
#define BB 8
#define QQ 2048
#define KK 2048
#define DD 512

typedef _Float16 f16x8 __attribute__((ext_vector_type(8)));
typedef float f32x4 __attribute__((ext_vector_type(4)));

__device__ __forceinline__ unsigned short f2h(float f) {
    union { _Float16 h; unsigned short u; } x;
    x.h = (_Float16)f;
    return x.u;
}
__device__ __forceinline__ float h2f(unsigned short u) {
    union { unsigned short u; _Float16 h; } x;
    x.u = u;
    return (float)x.h;
}

// async global->LDS, 16 B per lane; lds is wave-uniform base, HW scatters
// lane l to lds + l*16 (m97/m104 semantics).
__device__ __forceinline__ void async16(const unsigned short* g, unsigned short* l) {
    __builtin_amdgcn_global_load_lds(
        (const __attribute__((address_space(1))) unsigned int*)g,
        (__attribute__((address_space(3))) unsigned int*)l, 16, 0, 0);
}

// ---------------------------------------------------------------------------
// fp32 -> fp16 convert, 8 elems/thread, TWO tensors in one launch (y-dim).
// ---------------------------------------------------------------------------
__global__ __launch_bounds__(256) void cvt_f32_f16_2(const float* __restrict__ in0,
                                                     const float* __restrict__ in1,
                                                     unsigned short* __restrict__ out0,
                                                     unsigned short* __restrict__ out1) {
    const float* in = blockIdx.y ? in1 : in0;
    unsigned short* out = blockIdx.y ? out1 : out0;
    size_t i = ((size_t)blockIdx.x * 256 + threadIdx.x) * 8;
    float4 a = *(const float4*)(in + i);
    float4 b = *(const float4*)(in + i + 4);
    uint4 u;
    u.x = (unsigned)f2h(a.x) | ((unsigned)f2h(a.y) << 16);
    u.y = (unsigned)f2h(a.z) | ((unsigned)f2h(a.w) << 16);
    u.z = (unsigned)f2h(b.x) | ((unsigned)f2h(b.y) << 16);
    u.w = (unsigned)f2h(b.z) | ((unsigned)f2h(b.w) << 16);
    *(uint4*)(out + i) = u;
}

// ---------------------------------------------------------------------------
// Tiled transpose + convert: in[R][C] fp32 -> out[C][R] fp16 (32x32 tiles)
// ---------------------------------------------------------------------------
__global__ __launch_bounds__(256) void transpose_cvt(const float* __restrict__ in,
                                                     unsigned short* __restrict__ out,
                                                     int R, int C, long inB, long outB) {
    __shared__ float t[32][33];
    const float* ip = in + (size_t)blockIdx.z * inB;
    unsigned short* op = out + (size_t)blockIdx.z * outB;
    int x = threadIdx.x & 31, y0 = threadIdx.x >> 5;   // 32 x 8
    int c0 = blockIdx.x * 32, r0 = blockIdx.y * 32;
#pragma unroll
    for (int i = 0; i < 32; i += 8)
        t[y0 + i][x] = ip[(size_t)(r0 + y0 + i) * C + c0 + x];
    __syncthreads();
#pragma unroll
    for (int i = 0; i < 32; i += 8)
        op[(size_t)(c0 + y0 + i) * R + r0 + x] = f2h(t[x][y0 + i]);
}

// ---------------------------------------------------------------------------
// 128x128 NT GEMM, counted-vmcnt pipeline + multi-block TLP (R7-verified):
// 8 waves (2M x 4N, wave tile 64x32), BK=32, ring-3 LDS (48 KiB), prefetch
// distance 2, gate vmcnt(2) (never 0 in steady state), ONE s_barrier per
// K-tile, setprio'd 8-MFMA cluster, both-sides slot swizzle
// LDS[r][s] = G[r][s ^ ((r>>1)&3)].
// OUTM 0: f16 out (qW).
// OUTM 2: fp32 out scaled by 1/sums[row] (context) + FUSED dist epilogue:
//         after the K-loop, each (b,my,nx) block writes its
//         128-row x 512-col slice of dist = Sc * (1/rowsum) as fp32,
//         re-reading Sc from L2/L3 (it just streamed those bytes as the
//         A-operand). Fully coalesced: 64 consecutive lanes cover one row
//         slice (16B f16 reads -> 32B fp32 stores, full 128B lines).
//         Fixes both R2 failure modes (no vmcnt interference, no partial
//         lines) and deletes the normalize_rows pass.
// ---------------------------------------------------------------------------
template <int OUTM>
__global__ __launch_bounds__(512) void gemm128p(
    const unsigned short* __restrict__ Aall, const unsigned short* __restrict__ Ball,
    void* __restrict__ Call, const float* __restrict__ sums,
    float* __restrict__ distOut,
    int Kred, int lda, int ldb, int ldc,
    long aStride, long bStride, long cStride) {
    // ---- bijective XCD swizzle (m204) ----
    const int gx = gridDim.x, gy = gridDim.y;
    const int nwg = gx * gy * (int)gridDim.z;
    const int p = ((int)blockIdx.z * gy + (int)blockIdx.y) * gx + (int)blockIdx.x;
    const int qch = nwg >> 3, rch = nwg & 7;
    const int xcd = p & 7, ooff = p >> 3;
    const int w = (xcd < rch ? xcd * (qch + 1) : rch * (qch + 1) + (xcd - rch) * qch) + ooff;
    const int b = w / (gx * gy);
    const int rem = w - b * (gx * gy);
    const int my = rem / gx;
    const int nx = rem - my * gx;
    const int m0 = my * 128;
    const int n0 = nx * 128;

    __shared__ unsigned short As[3][128 * 32];   // 24 KiB
    __shared__ unsigned short Bs[3][128 * 32];   // 24 KiB

    const int tid = threadIdx.x;
    const int lane = tid & 63, wv = tid >> 6;    // 8 waves
    const int wm = wv >> 2, wn = wv & 3;         // 2M x 4N wave grid
    const int lrow = lane & 15, quad = lane >> 4;

    const int sr = lane >> 2;                    // row within 16-row chunk
    const int ssl = (lane & 3) ^ ((sr >> 1) & 3);  // pre-swizzled source slot
    const unsigned short* Ab = Aall + (size_t)b * aStride + (size_t)m0 * lda;
    const unsigned short* Bb = Ball + (size_t)b * bStride + (size_t)n0 * ldb;

    const int NT = Kred >> 5;

    // per wave per tile: 1 A-chunk + 1 B-chunk (chunk = 16 rows x 32 cols)
    auto stage = [&](int t, int slot) {
        const int r = wv * 16 + sr;
        async16(Ab + (size_t)r * lda + t * 32 + ssl * 8, &As[slot][wv * 512]);
        async16(Bb + (size_t)r * ldb + t * 32 + ssl * 8, &Bs[slot][wv * 512]);
    };

    f32x4 acc[4][2];
#pragma unroll
    for (int mi = 0; mi < 4; mi++)
#pragma unroll
        for (int ni = 0; ni < 2; ni++)
            acc[mi][ni] = (f32x4){0.f, 0.f, 0.f, 0.f};

    // prologue: stage tiles 0,1 (4 loads/wave in flight)
    stage(0, 0);
    if (NT > 1) stage(1, 1);

    const int rsw = (lrow >> 1) & 3;
    int sl = 0, slp = 2;                         // current slot, prefetch slot

    for (int t = 0; t < NT; ++t) {
        // gate: tile t's 2 loads retired; tile t+1's 2 may stay in flight
        if (t + 1 < NT) asm volatile("s_waitcnt vmcnt(2)" ::: "memory");
        else            asm volatile("s_waitcnt vmcnt(0)" ::: "memory");
        __builtin_amdgcn_s_barrier();
        __builtin_amdgcn_sched_barrier(0);

        const unsigned short* Asl = As[sl];
        const unsigned short* Bsl = Bs[sl];

        if (t + 2 < NT) stage(t + 2, slp);       // prefetch into ring

        f16x8 af[4], bfr[2];
#pragma unroll
        for (int ni = 0; ni < 2; ni++)
            bfr[ni] = *(const f16x8*)&Bsl[(wn * 32 + ni * 16 + lrow) * 32 + ((quad ^ rsw) * 8)];
#pragma unroll
        for (int mi = 0; mi < 4; mi++)
            af[mi] = *(const f16x8*)&Asl[(wm * 64 + mi * 16 + lrow) * 32 + ((quad ^ rsw) * 8)];

        __builtin_amdgcn_s_setprio(1);
#pragma unroll
        for (int mi = 0; mi < 4; mi++)
#pragma unroll
            for (int ni = 0; ni < 2; ni++)
                acc[mi][ni] = __builtin_amdgcn_mfma_f32_16x16x32_f16(af[mi], bfr[ni],
                                                                     acc[mi][ni], 0, 0, 0);
        __builtin_amdgcn_s_setprio(0);

        sl = (sl == 2) ? 0 : sl + 1;
        slp = (slp == 2) ? 0 : slp + 1;
    }

    // ---- epilogue ----
#pragma unroll
    for (int mi = 0; mi < 4; mi++) {
        const int gm = m0 + wm * 64 + mi * 16 + quad * 4;
        if constexpr (OUTM == 0) {
            unsigned short* C = (unsigned short*)Call + (size_t)b * cStride;
#pragma unroll
            for (int ni = 0; ni < 2; ni++) {
                int gn = n0 + wn * 32 + ni * 16 + lrow;
#pragma unroll
                for (int r = 0; r < 4; r++)
                    C[(size_t)(gm + r) * ldc + gn] = f2h(acc[mi][ni][r]);
            }
        } else {
            float* C = (float*)Call + (size_t)b * cStride;
            const float* s = sums + (size_t)b * QQ;
            float iv[4];
#pragma unroll
            for (int r = 0; r < 4; r++) iv[r] = 1.0f / s[gm + r];
#pragma unroll
            for (int ni = 0; ni < 2; ni++) {
                int gn = n0 + wn * 32 + ni * 16 + lrow;
#pragma unroll
                for (int r = 0; r < 4; r++)
                    C[(size_t)(gm + r) * ldc + gn] = acc[mi][ni][r] * iv[r];
            }
        }
    }

    // ---- fused dist epilogue (OUTM == 2 only) ----
    if constexpr (OUTM == 2) {
        // this block owns dist[b][m0..m0+128)[nx*512..(nx+1)*512)
        const unsigned short* ScP = Aall + (size_t)b * aStride + (size_t)m0 * lda + nx * 512;
        float* dp = distOut + (size_t)b * QQ * KK + (size_t)m0 * KK + nx * 512;
        const float* s = sums + (size_t)b * QQ + m0;
        // flat mapping: 64 consecutive lanes = one 512-col row slice
        // (8 f16 per lane); 512 threads cover 8 rows/iter, 16 iters.
#pragma unroll 4
        for (int it = 0; it < 16; ++it) {
            const int e = (tid + it * 512) * 8;        // elem in 128x512 slice
            const int row = e >> 9, col = e & 511;
            f16x8 h = *(const f16x8*)&ScP[(size_t)row * lda + col];
            const float inv = 1.0f / s[row];           // wave-uniform (64 lanes/row)
            f32x4 o0 = {(float)h[0] * inv, (float)h[1] * inv,
                        (float)h[2] * inv, (float)h[3] * inv};
            f32x4 o1 = {(float)h[4] * inv, (float)h[5] * inv,
                        (float)h[6] * inv, (float)h[7] * inv};
            *(f32x4*)&dp[(size_t)row * KK + col] = o0;
            *(f32x4*)&dp[(size_t)row * KK + col + 4] = o1;
        }
    }
}

// ---------------------------------------------------------------------------
// Deep-pipelined 256x256 NT GEMM with exp/mask/rowsum epilogue (scores step).
// HW-verified in R5. 8 waves (2M x 4N), BK=32, quad-buffered LDS ring,
// prefetch distance 3, counted vmcnt gates (8/4/0), ONE raw s_barrier per
// K-tile, setprio'd 16-MFMA clusters, both-sides slot swizzle.
// ---------------------------------------------------------------------------
__global__ __launch_bounds__(512, 2) void gemm256_exp(
    const unsigned short* __restrict__ Aall, const unsigned short* __restrict__ Ball,
    unsigned short* __restrict__ Call, const int* __restrict__ maskAll,
    float* __restrict__ sums, int Kred, int lda, int ldb, int ldc,
    long aStride, long bStride, long cStride, int maskStride, float scale) {
    // ---- bijective XCD swizzle ----
    const int gx = gridDim.x, gy = gridDim.y;
    const int nwg = gx * gy * (int)gridDim.z;
    const int p = ((int)blockIdx.z * gy + (int)blockIdx.y) * gx + (int)blockIdx.x;
    const int qch = nwg >> 3, rch = nwg & 7;
    const int xcd = p & 7, ooff = p >> 3;
    const int w = (xcd < rch ? xcd * (qch + 1) : rch * (qch + 1) + (xcd - rch) * qch) + ooff;
    const int b = w / (gx * gy);
    const int rem = w - b * (gx * gy);
    const int my = rem / gx;
    const int nx = rem - my * gx;
    const int m0 = my * 256;
    const int n0 = nx * 256;

    __shared__ unsigned short As[4][256 * 32];   // 64 KiB ring
    __shared__ unsigned short Bs[4][256 * 32];   // 64 KiB ring

    const int tid = threadIdx.x;
    const int lane = tid & 63, wv = tid >> 6;    // 8 waves
    const int wm = wv >> 2, wn = wv & 3;         // 2 x 4 wave grid
    const int lrow = lane & 15, quad = lane >> 4;

    const int sr = lane >> 2;
    const int ssl = (lane & 3) ^ ((sr >> 1) & 3);
    const unsigned short* Ab = Aall + (size_t)b * aStride + (size_t)m0 * lda;
    const unsigned short* Bb = Ball + (size_t)b * bStride + (size_t)n0 * ldb;

    const int NT = Kred >> 5;

    auto stageA = [&](int t) {
#pragma unroll
        for (int j = 0; j < 2; j++) {
            const int c = wv * 2 + j;
            const int r = c * 16 + sr;
            async16(Ab + (size_t)r * lda + t * 32 + ssl * 8, &As[t & 3][c * 512]);
        }
    };
    auto stageB = [&](int t) {
#pragma unroll
        for (int j = 0; j < 2; j++) {
            const int c = wv * 2 + j;
            const int r = c * 16 + sr;
            async16(Bb + (size_t)r * ldb + t * 32 + ssl * 8, &Bs[t & 3][c * 512]);
        }
    };

    f32x4 acc[8][4];
#pragma unroll
    for (int mi = 0; mi < 8; mi++)
#pragma unroll
        for (int ni = 0; ni < 4; ni++)
            acc[mi][ni] = (f32x4){0.f, 0.f, 0.f, 0.f};

    for (int tt = 0; tt < 3 && tt < NT; ++tt) { stageA(tt); stageB(tt); }

    const int rsw = (lrow >> 1) & 3;

    for (int t = 0; t < NT; ++t) {
        if (t + 2 < NT)      asm volatile("s_waitcnt vmcnt(8)" ::: "memory");
        else if (t + 1 < NT) asm volatile("s_waitcnt vmcnt(4)" ::: "memory");
        else                 asm volatile("s_waitcnt vmcnt(0)" ::: "memory");
        __builtin_amdgcn_s_barrier();
        __builtin_amdgcn_sched_barrier(0);

        const unsigned short* Asl = As[t & 3];
        const unsigned short* Bsl = Bs[t & 3];
        f16x8 af[4], bfr[4];

        if (t + 3 < NT) stageA(t + 3);
#pragma unroll
        for (int ni = 0; ni < 4; ni++)
            bfr[ni] = *(const f16x8*)&Bsl[(wn * 64 + ni * 16 + lrow) * 32 + ((quad ^ rsw) * 8)];
#pragma unroll
        for (int mi = 0; mi < 4; mi++)
            af[mi] = *(const f16x8*)&Asl[(wm * 128 + mi * 16 + lrow) * 32 + ((quad ^ rsw) * 8)];
        __builtin_amdgcn_s_setprio(1);
#pragma unroll
        for (int mi = 0; mi < 4; mi++)
#pragma unroll
            for (int ni = 0; ni < 4; ni++)
                acc[mi][ni] = __builtin_amdgcn_mfma_f32_16x16x32_f16(af[mi], bfr[ni],
                                                                     acc[mi][ni], 0, 0, 0);
        __builtin_amdgcn_s_setprio(0);

        if (t + 3 < NT) stageB(t + 3);
#pragma unroll
        for (int mi = 0; mi < 4; mi++)
            af[mi] = *(const f16x8*)&Asl[(wm * 128 + (mi + 4) * 16 + lrow) * 32 + ((quad ^ rsw) * 8)];
        __builtin_amdgcn_s_setprio(1);
#pragma unroll
        for (int mi = 0; mi < 4; mi++)
#pragma unroll
            for (int ni = 0; ni < 4; ni++)
                acc[mi + 4][ni] = __builtin_amdgcn_mfma_f32_16x16x32_f16(af[mi], bfr[ni],
                                                                         acc[mi + 4][ni], 0, 0, 0);
        __builtin_amdgcn_s_setprio(0);
    }

    // ---- epilogue: e = mask ? exp(acc*scale) : 0 -> f16 out; rowsum atomics ----
    unsigned short* C = Call + (size_t)b * cStride;
    const int* mk = maskAll + (size_t)b * maskStride;
#pragma unroll
    for (int mi = 0; mi < 8; mi++) {
        const int gm = m0 + wm * 128 + mi * 16 + quad * 4;
        float ps[4] = {0.f, 0.f, 0.f, 0.f};
#pragma unroll
        for (int ni = 0; ni < 4; ni++) {
            int gn = n0 + wn * 64 + ni * 16 + lrow;
            bool keep = mk[gn] != 0;
#pragma unroll
            for (int r = 0; r < 4; r++) {
                float e = keep ? __expf(acc[mi][ni][r] * scale) : 0.f;
                C[(size_t)(gm + r) * ldc + gn] = f2h(e);
                ps[r] += e;
            }
        }
#pragma unroll
        for (int off = 1; off < 16; off <<= 1)
#pragma unroll
            for (int r = 0; r < 4; r++) ps[r] += __shfl_xor(ps[r], off);
        if (lrow == 0) {
            float* s = sums + (size_t)b * QQ;
#pragma unroll
            for (int r = 0; r < 4; r++) atomicAdd(&s[gm + r], ps[r]);
        }
    }
}

// ---------------------------------------------------------------------------
extern "C" void kernel_launch(void* const* d_in, const int* in_sizes, int n_in,
                              void* d_out, int out_size, void* d_ws, size_t ws_size,
                              hipStream_t stream) {
    const float* q    = (const float*)d_in[0];   // [B,Q,D]
    const float* k    = (const float*)d_in[1];   // [B,K,D]
    const float* v    = (const float*)d_in[2];   // [B,K,D]
    const int*   mask = (const int*)d_in[3];     // [B,K]
    const float* W    = (const float*)d_in[4];   // [D,D]

    float* ctx  = (float*)d_out;                           // [B,Q,D]
    float* dist = ctx + (size_t)BB * QQ * DD;              // [B,Q,K]

    // workspace layout (f16 = unsigned short), ~135 MiB
    unsigned short* ws  = (unsigned short*)d_ws;
    unsigned short* Wt  = ws;                                   // [D][D]   (W^T)
    unsigned short* Qh  = Wt + (size_t)DD * DD;                 // [B][Q][D]
    unsigned short* Kh  = Qh + (size_t)BB * QQ * DD;            // [B][K][D]
    unsigned short* Vt  = Kh + (size_t)BB * KK * DD;            // [B][D][K] (V^T)
    unsigned short* qWh = Vt + (size_t)BB * DD * KK;            // [B][Q][D]
    unsigned short* Sc  = qWh + (size_t)BB * QQ * DD;           // [B][Q][K] expS f16
    float* sums = (float*)(Sc + (size_t)BB * QQ * KK);          // [B][Q]

    const float scale = 0.044194173824159216f;  // 1/sqrt(512)

    // 0) zero the row-sum accumulators (graph-capture-legal async memset)
    (void)hipMemsetAsync(sums, 0, (size_t)BB * QQ * sizeof(float), stream);
    // 1) W -> W^T f16
    transpose_cvt<<<dim3(DD / 32, DD / 32, 1), 256, 0, stream>>>(W, Wt, DD, DD, 0, 0);
    // 2) query, key -> f16 (single launch)
    cvt_f32_f16_2<<<dim3((BB * QQ * DD / 8) / 256, 2), 256, 0, stream>>>(q, k, Qh, Kh);
    // 3) value -> V^T f16
    transpose_cvt<<<dim3(DD / 32, KK / 32, BB), 256, 0, stream>>>(
        v, Vt, KK, DD, (long)KK * DD, (long)DD * KK);
    // 4) qW[b] = Q[b] @ W: M=Q, N=D, Kred=D -> f16 (R7-verified 8-wave 128-tile)
    gemm128p<0><<<dim3(DD / 128, QQ / 128, BB), 512, 0, stream>>>(
        Qh, Wt, qWh, nullptr, nullptr, DD, DD, DD, DD,
        (long)QQ * DD, 0, (long)QQ * DD);
    // 5) expS[b] = exp(scale * qW[b] @ key[b]^T) (masked->0) + row sums
    gemm256_exp<<<dim3(KK / 256, QQ / 256, BB), 512, 0, stream>>>(
        qWh, Kh, Sc, mask, sums, DD, DD, DD, KK,
        (long)QQ * DD, (long)KK * DD, (long)QQ * KK, KK, scale);
    // 6+7) context[b] = (expS[b] @ value[b]) / rowsum, with FUSED
    //      dist = expS/rowsum epilogue (replaces normalize_rows)
    gemm128p<2><<<dim3(DD / 128, QQ / 128, BB), 512, 0, stream>>>(
        Sc, Vt, ctx, sums, dist, KK, KK, KK, DD,
        (long)QQ * KK, (long)DD * KK, (long)QQ * DD);
}